// Round 5
// baseline (8077.723 us; speedup 1.0000x reference)
//
#include <hip/hip_runtime.h>
#include <math.h>

#define T_SEQ 4096

__device__ __forceinline__ float sigmoidf_(float x) {
  return 1.0f / (1.0f + expf(-x));
}

__device__ __forceinline__ unsigned long long pack_h(int tag, float h) {
  return ((unsigned long long)(unsigned)tag << 32) |
         (unsigned long long)__float_as_uint(h);
}

// Fast probe: L1-bypassing load served by the XCD's L2 (shared with the
// producer under the claim scheme). The fast-slot lines are NEVER touched by
// system-scope ops, so they stay resident+updated in L2.
__device__ __forceinline__ unsigned long long ld_l2(const unsigned long long* p) {
  unsigned long long v;
  asm volatile("global_load_dwordx2 %0, %1, off sc0\n\ts_waitcnt vmcnt(0)"
               : "=v"(v) : "v"(p) : "memory");
  return v;
}
// System-scope load: device truth at the MALL (progress guarantee).
__device__ __forceinline__ unsigned long long ld_mall(const unsigned long long* p) {
  unsigned long long v;
  asm volatile("global_load_dwordx2 %0, %1, off sc0 sc1\n\ts_waitcnt vmcnt(0)"
               : "=v"(v) : "v"(p) : "memory");
  return v;
}
// Publish, now split across TWO DIFFERENT cache lines:
//  - fast slot: plain store -> write-through into local L2, line stays valid
//    (R0-R4 bug: same-address plain+system stores were coalesced; the system
//    store invalidated the L2 line and pollers re-installed stale MALL data
//    faster than the publish could land -> fast probes NEVER detected).
//  - truth copy: system-scope store -> MALL, cross-XCD fallback.
__device__ __forceinline__ void st_fast(unsigned long long* p, unsigned long long v) {
  asm volatile("global_store_dwordx2 %0, %1, off"
               :: "v"(p), "v"(v) : "memory");
}
__device__ __forceinline__ void st_mall(unsigned long long* p, unsigned long long v) {
  asm volatile("global_store_dwordx2 %0, %1, off sc0 sc1"
               :: "v"(p), "v"(v) : "memory");
}

// Exact-tag poll: 3 fast L2 probes on the fast slot, every 4th probes the
// truth address at the MALL. Used where slot overwrite is impossible
// (sibling WGs are <=2 publishes apart; 2-parity slots).
__device__ __forceinline__ float poll_dual(const unsigned long long* fast_p,
                                           const unsigned long long* truth_p,
                                           unsigned want) {
  int it = 0;
  for (;;) {
    unsigned long long v = ((it & 3) == 3) ? ld_mall(truth_p) : ld_l2(fast_p);
    if ((unsigned)(v >> 32) == want) return __uint_as_float((unsigned)v);
    ++it;
  }
}
// h0->L1 poll: the consumer may lag the producer arbitrarily, so the fast
// slot can be overwritten (tag > want) -> switch permanently to the truth
// ring (full history, MALL). Never wrong, never hung.
__device__ __forceinline__ float poll_h0(const unsigned long long* fast_p,
                                         const unsigned long long* truth_p,
                                         unsigned want) {
  int it = 0;
  for (;;) {
    if ((it & 3) == 3) {
      unsigned long long v = ld_mall(truth_p);
      if ((unsigned)(v >> 32) == want) return __uint_as_float((unsigned)v);
    } else {
      unsigned long long v = ld_l2(fast_p);
      unsigned tag = (unsigned)(v >> 32);
      if (tag == want) return __uint_as_float((unsigned)v);
      if (tag > want) break;   // slot overwritten -> truth only
    }
    ++it;
  }
  for (;;) {
    unsigned long long v = ld_mall(truth_p);
    if ((unsigned)(v >> 32) == want) return __uint_as_float((unsigned)v);
  }
}

// Raw workgroup barrier: drains LDS (lgkmcnt) only — publishes/prefetches
// stay in flight across barriers.
__device__ __forceinline__ void bar() {
  asm volatile("s_waitcnt lgkmcnt(0)" ::: "memory");
  __builtin_amdgcn_s_barrier();
  asm volatile("" ::: "memory");
}

// ---- named-register weight fragments + anti-rematerialization pin ----------
#define DECL_W8(p) float4 p##0, p##1, p##2, p##3, p##4, p##5, p##6, p##7
#define LOAD_W8(p, src) do { const float4* _s = (const float4*)(src); \
  p##0=_s[0]; p##1=_s[1]; p##2=_s[2]; p##3=_s[3]; \
  p##4=_s[4]; p##5=_s[5]; p##6=_s[6]; p##7=_s[7]; } while (0)
#define PIN4(v4) asm volatile("" : "+v"((v4).x), "+v"((v4).y), \
                                   "+v"((v4).z), "+v"((v4).w))
#define PIN_W8(p) do { PIN4(p##0); PIN4(p##1); PIN4(p##2); PIN4(p##3); \
  PIN4(p##4); PIN4(p##5); PIN4(p##6); PIN4(p##7); } while (0)
#define FMA4(acc, W_, H_) do { acc = fmaf((W_).x, (H_).x, acc); \
  acc = fmaf((W_).y, (H_).y, acc); acc = fmaf((W_).z, (H_).z, acc); \
  acc = fmaf((W_).w, (H_).w, acc); } while (0)

// X[t][k] = emb[tokens[t]][k], as float4
__global__ void gather_emb(const int* __restrict__ tokens,
                           const float4* __restrict__ emb4,
                           float4* __restrict__ X4) {
  int i = blockIdx.x * 256 + threadIdx.x;   // i < 4096*128
  int t = i >> 7;
  int q = i & 127;
  X4[i] = emb4[(long)tokens[t] * 128 + q];
}

// P[t][j] = bias_ih[j] + bias_hh[j] + sum_k X[src(t)][k] * W[j][k]
__global__ __launch_bounds__(256) void gemm_proj(
    const float* __restrict__ Xf, const float* __restrict__ Xb, int revb,
    const float* __restrict__ Wf, const float* __restrict__ Wb,
    const float* __restrict__ bihf, const float* __restrict__ bhhf,
    const float* __restrict__ bihb, const float* __restrict__ bhhb,
    float* __restrict__ Pf, float* __restrict__ Pb, int K)
{
  const int dirb = blockIdx.z;
  const float* X  = dirb ? Xb : Xf;
  const float* W  = dirb ? Wb : Wf;
  const float* bih = dirb ? bihb : bihf;
  const float* bhh = dirb ? bhhb : bhhf;
  float* Pp = dirb ? Pb : Pf;
  const int rev = dirb ? revb : 0;

  const int bn = blockIdx.x;   // N tile (16)
  const int bm = blockIdx.y;   // M tile (64)
  const int tid = threadIdx.x;
  const int tx = tid & 15, ty = tid >> 4;

  __shared__ float Xs[16][68];
  __shared__ float Ws[16][68];

  float acc[4][4] = {{0.f}};

  const int lrow = tid >> 2;
  const int lk4  = (tid & 3) * 4;
  const int xrow = bm * 64 + lrow;
  const int xsrc = rev ? (4095 - xrow) : xrow;
  const float* xptr = X + (long)xsrc * K + lk4;
  const float* wptr = W + (long)(bn * 64 + lrow) * K + lk4;

  for (int k0 = 0; k0 < K; k0 += 16) {
    float4 xv = *(const float4*)(xptr + k0);
    float4 wv = *(const float4*)(wptr + k0);
    __syncthreads();
    Xs[lk4 + 0][lrow] = xv.x; Xs[lk4 + 1][lrow] = xv.y;
    Xs[lk4 + 2][lrow] = xv.z; Xs[lk4 + 3][lrow] = xv.w;
    Ws[lk4 + 0][lrow] = wv.x; Ws[lk4 + 1][lrow] = wv.y;
    Ws[lk4 + 2][lrow] = wv.z; Ws[lk4 + 3][lrow] = wv.w;
    __syncthreads();
    #pragma unroll
    for (int kk = 0; kk < 16; ++kk) {
      float4 a = *(const float4*)(&Xs[kk][ty * 4]);
      float4 b = *(const float4*)(&Ws[kk][tx * 4]);
      acc[0][0] = fmaf(a.x, b.x, acc[0][0]); acc[0][1] = fmaf(a.x, b.y, acc[0][1]);
      acc[0][2] = fmaf(a.x, b.z, acc[0][2]); acc[0][3] = fmaf(a.x, b.w, acc[0][3]);
      acc[1][0] = fmaf(a.y, b.x, acc[1][0]); acc[1][1] = fmaf(a.y, b.y, acc[1][1]);
      acc[1][2] = fmaf(a.y, b.z, acc[1][2]); acc[1][3] = fmaf(a.y, b.w, acc[1][3]);
      acc[2][0] = fmaf(a.z, b.x, acc[2][0]); acc[2][1] = fmaf(a.z, b.y, acc[2][1]);
      acc[2][2] = fmaf(a.z, b.z, acc[2][2]); acc[2][3] = fmaf(a.z, b.w, acc[2][3]);
      acc[3][0] = fmaf(a.w, b.x, acc[3][0]); acc[3][1] = fmaf(a.w, b.y, acc[3][1]);
      acc[3][2] = fmaf(a.w, b.z, acc[3][2]); acc[3][3] = fmaf(a.w, b.w, acc[3][3]);
    }
  }

  const int c0 = bn * 64 + tx * 4;
  #pragma unroll
  for (int i = 0; i < 4; ++i) {
    const int r = bm * 64 + ty * 4 + i;
    float4 o4;
    o4.x = acc[i][0] + bih[c0 + 0] + bhh[c0 + 0];
    o4.y = acc[i][1] + bih[c0 + 1] + bhh[c0 + 1];
    o4.z = acc[i][2] + bih[c0 + 2] + bhh[c0 + 2];
    o4.w = acc[i][3] + bih[c0 + 3] + bhh[c0 + 3];
    *(float4*)(&Pp[(long)r * 1024 + c0]) = o4;
  }
}

// Fused 2-layer bidirectional LSTM recurrence with XCD colocation BY
// CONSTRUCTION (s_getreg HW_REG_XCC_ID + claim table) and SPLIT-ADDRESS
// publish/poll: fast parity slots (plain store / sc0 probe, L2-resident) +
// truth ring/slots (system store / system probe, MALL).
//
// Roles per direction (12): r 0-3 = L0 (64 cells each), r 4-11 = L1 (32 cells
// each, K=512). Row mapping m = cell*4 + gate; i/f/g/o combine is 3 in-wave
// shuffles. 2 raw barriers per step (lgkmcnt-only).
__global__ __launch_bounds__(512, 1) void lstm_fused(
    const float* __restrict__ P0f, const float* __restrict__ P0b,
    const float* __restrict__ Whh0f, const float* __restrict__ Whh0b,
    const float* __restrict__ Wih1f, const float* __restrict__ Whh1f,
    const float* __restrict__ bih1f, const float* __restrict__ bhh1f,
    const float* __restrict__ Wih1b, const float* __restrict__ Whh1b,
    const float* __restrict__ bih1b, const float* __restrict__ bhh1b,
    float* __restrict__ out,
    unsigned long long* __restrict__ ring0,   // truth: [2 dirs][4096][256]
    unsigned long long* __restrict__ h1x,     // truth: [2 dirs][2 par][256]
    unsigned long long* __restrict__ l0fast,  // fast:  [2 dirs][2 par][256]
    unsigned long long* __restrict__ h1fast,  // fast:  [2 dirs][2 par][256]
    int* __restrict__ claim)                  // cnt[0..8], xdir[0..7]
{
  const int t = threadIdx.x;

  __shared__ int s_dir, s_sub;
  __shared__ float hx[512];        // L0: h[256]; L1: h0[s] ++ h1[s-1]
  __shared__ float part[8 * 264];  // [k-slice][row m=cell*4+gate], padded

  // ---- XCD role claim -------------------------------------------------------
  int hwv;
  asm volatile("s_getreg_b32 %0, hwreg(HW_REG_XCC_ID)" : "=s"(hwv));
  const int myxcd = hwv & 7;
  if (t == 0) {
    int* cnt  = claim;
    int* xdir = claim + 16;
    int r = atomicAdd(&cnt[myxcd], 1);
    if (r == 0) {
      int dslot = atomicAdd(&cnt[8], 1);
      atomicExch(&xdir[myxcd], (dslot < 2) ? (dslot + 1) : 3);
    }
    int dv;
    do { dv = atomicAdd(&xdir[myxcd], 0); } while (dv == 0);
    s_dir = (dv <= 2 && r < 12) ? (dv - 1) : -1;
    s_sub = r;
  }
  __syncthreads();
  if (s_dir < 0) return;
  const int d   = s_dir;   // 0 = forward, 1 = backward
  const int sub = s_sub;   // role within direction, 0..11

  unsigned long long* ring = ring0 + (long)d * T_SEQ * 256;
  unsigned long long* l0f  = l0fast + (long)d * 512;   // [parity][256]
  unsigned long long* h1f  = h1fast + (long)d * 512;   // [parity][256]

  if (sub < 4) {
    // ======================= Layer 0 (4 WGs/dir, 64 cells) ==================
    const int w = sub;
    const int wbase = w * 64;
    const float* __restrict__ P = d ? P0b : P0f;
    const float* __restrict__ W = d ? Whh0b : Whh0f;

    const int kb = t >> 6;   // k-slice 0..7 (32 k each)
    const int jg = t & 63;   // cell served by this B-thread

    // Weight rows for (cell=jg, gate=0..3), k-slice kb, pinned in registers.
    DECL_W8(wa); DECL_W8(wb); DECL_W8(wc); DECL_W8(wd);
    LOAD_W8(wa, W + (long)(0 * 256 + wbase + jg) * 256 + kb * 32);
    LOAD_W8(wb, W + (long)(1 * 256 + wbase + jg) * 256 + kb * 32);
    LOAD_W8(wc, W + (long)(2 * 256 + wbase + jg) * 256 + kb * 32);
    LOAD_W8(wd, W + (long)(3 * 256 + wbase + jg) * 256 + kb * 32);
    PIN_W8(wa); PIN_W8(wb); PIN_W8(wc); PIN_W8(wd);

    // C-thread t<256 handles row m=t: cell=t>>2, gate=t&3.
    const long pj = (long)((t & 3) * 256 + wbase + (t >> 2));

    float pv_cur = 0.0f, c_prev = 0.0f;
    if (t < 256) { pv_cur = P[pj]; hx[t] = 0.0f; }

    for (int s = 0; s < T_SEQ; ++s) {
      // -------- A: dedicated pollers fetch sibling h(s-1) ------------------
      if (s > 0 && t >= 256 && t < 448) {
        const int q = t - 256;
        const int pcell = (q < wbase) ? q : q + 64;
        hx[pcell] = poll_dual(l0f + ((s - 1) & 1) * 256 + pcell,
                              ring + (long)(s - 1) * 256 + pcell, (unsigned)s);
      }
      float pv_next = 0.0f;
      if (t < 256 && s + 1 < T_SEQ) pv_next = P[(long)(s + 1) * 1024 + pj];
      bar();   // Y: hx(s-1) complete (pollers + prev combine's own-cell write)

      // -------- B: matvec from pinned-register weights ---------------------
      float a0 = 0.f, a1 = 0.f, a2 = 0.f, a3 = 0.f;
      const float4* h4 = (const float4*)&hx[kb * 32];
      #define L0STEP(q) do { float4 hv = h4[q]; FMA4(a0, wa##q, hv); \
        FMA4(a1, wb##q, hv); FMA4(a2, wc##q, hv); FMA4(a3, wd##q, hv); } while (0)
      L0STEP(0); L0STEP(1); L0STEP(2); L0STEP(3);
      L0STEP(4); L0STEP(5); L0STEP(6); L0STEP(7);
      #undef L0STEP
      float4 av; av.x = a0; av.y = a1; av.z = a2; av.w = a3;
      *(float4*)(&part[kb * 264 + jg * 4]) = av;   // rows m=jg*4+gate
      bar();   // 2: part[] complete

      // -------- C: activation + in-wave quad combine + publish -------------
      if (t < 256) {
        float g = pv_cur;
        #pragma unroll
        for (int q = 0; q < 8; ++q) g += part[q * 264 + t];
        float act = ((t & 3) == 2) ? tanhf(g) : sigmoidf_(g);
        float y  = __shfl_xor(act, 1);
        float zx = __shfl_xor(act, 2);
        float zy = __shfl_xor(y, 2);
        const bool l1b = (t & 1), h1b = (t & 2);
        float i_ = h1b ? (l1b ? zy : zx) : (l1b ? y : act);
        float f_ = h1b ? (l1b ? zx : zy) : (l1b ? act : y);
        float g_ = h1b ? (l1b ? y : act) : (l1b ? zy : zx);
        float o_ = h1b ? (l1b ? act : y) : (l1b ? zx : zy);
        float c = f_ * c_prev + i_ * g_;
        c_prev = c;
        float h = o_ * tanhf(c);
        pv_cur = pv_next;
        if ((t & 3) == 0) {
          const int gc = wbase + (t >> 2);
          hx[gc] = h;                                   // own-cell LDS bypass
          unsigned long long pk = pack_h(s + 1, h);
          st_fast(l0f + (s & 1) * 256 + gc, pk);        // fast slot (L2)
          st_mall(ring + (long)s * 256 + gc, pk);       // truth (MALL)
          if (s == T_SEQ - 1) {
            out[d * 256 + gc] = c;            // cell_memories layer 0
            out[1024 + d * 256 + gc] = h;     // hidden_states layer 0
          }
        }
      }
      // no barrier here: next iteration's barY orders C writes vs B reads.
    }
  } else {
    // ======================= Layer 1 (8 WGs/dir, 32 cells) ==================
    const int w1 = sub - 4;   // 0..7
    const int wbase1 = w1 * 32;
    const float* __restrict__ Wih = d ? Wih1b : Wih1f;
    const float* __restrict__ Whh = d ? Whh1b : Whh1f;
    const float* __restrict__ bih = d ? bih1b : bih1f;
    const float* __restrict__ bhh = d ? bhh1b : bhh1f;
    unsigned long long* slot = h1x + d * 512;            // truth [parity][256]
    float* hout = d ? (out + 2048 + (long)4095 * 512 + 256) : (out + 2048);
    const long hstr = d ? -512 : 512;

    const int kb = t >> 6;   // k-slice 0..7 (64 k each of combined K=512)
    const int jg = t & 63;   // -> 2 rows m = jg*2, jg*2+1 (m in [0,128))

    const int m0 = jg * 2, m1 = m0 + 1;
    const int j0 = (m0 & 3) * 256 + wbase1 + (m0 >> 2);
    const int j1 = (m1 & 3) * 256 + wbase1 + (m1 >> 2);
    const float* s0 = (kb < 4) ? (Wih + (long)j0 * 256 + kb * 64)
                               : (Whh + (long)j0 * 256 + (kb - 4) * 64);
    const float* s1 = (kb < 4) ? (Wih + (long)j1 * 256 + kb * 64)
                               : (Whh + (long)j1 * 256 + (kb - 4) * 64);
    DECL_W8(ua); DECL_W8(ub); DECL_W8(uc); DECL_W8(ud);
    LOAD_W8(ua, s0); LOAD_W8(ub, s0 + 32);
    LOAD_W8(uc, s1); LOAD_W8(ud, s1 + 32);
    PIN_W8(ua); PIN_W8(ub); PIN_W8(uc); PIN_W8(ud);

    float bsum = 0.0f, c_prev = 0.0f;
    if (t < 128) {   // C-thread t handles row m=t: cell=t>>2, gate=t&3
      const int j = (t & 3) * 256 + wbase1 + (t >> 2);
      bsum = bih[j] + bhh[j];
      if ((t & 3) == 0) hx[256 + wbase1 + (t >> 2)] = 0.0f;  // own h1(-1)=0
    }

    for (int s = 0; s < T_SEQ; ++s) {
      // -------- A: poll h0(s) (256) + sibling h1(s-1) (224) ----------------
      if (t >= 128 && t < 384) {
        const int c0_ = t - 128;
        hx[c0_] = poll_h0(l0f + (s & 1) * 256 + c0_,
                          ring + (long)s * 256 + c0_, (unsigned)(s + 1));
      } else {
        int q1 = -1;
        if (t < 128) { if ((t & 3) != 0) q1 = (t >> 2) * 3 + (t & 3) - 1; }
        else q1 = 96 + (t - 384);
        if (q1 >= 0) {
          const int pc1 = (q1 < wbase1) ? q1 : q1 + 32;
          hx[256 + pc1] = poll_dual(h1f + ((s + 1) & 1) * 256 + pc1,
                                    slot + ((s + 1) & 1) * 256 + pc1,
                                    (unsigned)s);
        }
      }
      bar();   // Y

      // -------- B: matvec over K=512 ---------------------------------------
      float a0 = 0.f, a1 = 0.f;
      const float4* h4 = (const float4*)&hx[kb * 64];
      #define L1STEPA(q) do { float4 hv = h4[q];     FMA4(a0, ua##q, hv); \
        FMA4(a1, uc##q, hv); } while (0)
      #define L1STEPB(q) do { float4 hv = h4[8 + q]; FMA4(a0, ub##q, hv); \
        FMA4(a1, ud##q, hv); } while (0)
      L1STEPA(0); L1STEPA(1); L1STEPA(2); L1STEPA(3);
      L1STEPA(4); L1STEPA(5); L1STEPA(6); L1STEPA(7);
      L1STEPB(0); L1STEPB(1); L1STEPB(2); L1STEPB(3);
      L1STEPB(4); L1STEPB(5); L1STEPB(6); L1STEPB(7);
      #undef L1STEPA
      #undef L1STEPB
      float2 av2; av2.x = a0; av2.y = a1;
      *(float2*)(&part[kb * 264 + jg * 2]) = av2;
      bar();   // 2

      // -------- C: activation + quad combine + publish ---------------------
      if (t < 128) {
        float g = bsum;
        #pragma unroll
        for (int q = 0; q < 8; ++q) g += part[q * 264 + t];
        float act = ((t & 3) == 2) ? tanhf(g) : sigmoidf_(g);
        float y  = __shfl_xor(act, 1);
        float zx = __shfl_xor(act, 2);
        float zy = __shfl_xor(y, 2);
        const bool l1b = (t & 1), h1b = (t & 2);
        float i_ = h1b ? (l1b ? zy : zx) : (l1b ? y : act);
        float f_ = h1b ? (l1b ? zx : zy) : (l1b ? act : y);
        float g_ = h1b ? (l1b ? y : act) : (l1b ? zy : zx);
        float o_ = h1b ? (l1b ? act : y) : (l1b ? zx : zy);
        float c = f_ * c_prev + i_ * g_;
        c_prev = c;
        float h = o_ * tanhf(c);
        if ((t & 3) == 0) {
          const int gc = wbase1 + (t >> 2);
          hx[256 + gc] = h;                            // own-cell LDS bypass
          unsigned long long pk = pack_h(s + 1, h);
          st_fast(h1f + (s & 1) * 256 + gc, pk);       // fast slot (L2)
          st_mall(&slot[(s & 1) * 256 + gc], pk);      // truth (MALL)
          hout[(long)s * hstr + gc] = h;
          if (s == T_SEQ - 1) {
            out[512 + d * 256 + gc] = c;          // cell_memories layer 1
            out[1024 + 512 + d * 256 + gc] = h;   // hidden_states layer 1
          }
        }
      }
    }
  }
}

extern "C" void kernel_launch(void* const* d_in, const int* in_sizes, int n_in,
                              void* d_out, int out_size, void* d_ws, size_t ws_size,
                              hipStream_t stream) {
  const int*   tokens = (const int*)d_in[0];
  const float* emb    = (const float*)d_in[1];
  const float* fWih0 = (const float*)d_in[2];
  const float* fWhh0 = (const float*)d_in[3];
  const float* fbih0 = (const float*)d_in[4];
  const float* fbhh0 = (const float*)d_in[5];
  const float* fWih1 = (const float*)d_in[6];
  const float* fWhh1 = (const float*)d_in[7];
  const float* fbih1 = (const float*)d_in[8];
  const float* fbhh1 = (const float*)d_in[9];
  const float* bWih0 = (const float*)d_in[10];
  const float* bWhh0 = (const float*)d_in[11];
  const float* bbih0 = (const float*)d_in[12];
  const float* bbhh0 = (const float*)d_in[13];
  const float* bWih1 = (const float*)d_in[14];
  const float* bWhh1 = (const float*)d_in[15];
  const float* bbih1 = (const float*)d_in[16];
  const float* bbhh1 = (const float*)d_in[17];

  float* out = (float*)d_out;
  float* ws  = (float*)d_ws;

  // Workspace layout (float offsets):
  //   [0, 4194304)          h0 truth rings: [2 dirs][4096][256] u64 (16 MB).
  //                         X (4096x512, 8 MB) overlaps [0, 2097152) — dead
  //                         after gemm_proj; rings memset afterwards.
  //   [4194304,  8388608)   P0f (4096x1024)
  //   [8388608, 12582912)   P0b (4096x1024)
  //   [12582912, 12584960)  h1x truth: [2 dirs][2 par][256] u64 (8 KB)
  //   [12584960, 12584992)  claim table: cnt[0..8], xdir[0..7] (32 ints)
  //   [12584992, 12587040)  l0fast: [2 dirs][2 par][256] u64 (8 KB)
  //   [12587040, 12589088)  h1fast: [2 dirs][2 par][256] u64 (8 KB)
  float* X   = ws;
  float* P0f = ws + 4194304;
  float* P0b = ws + 8388608;
  unsigned long long* ring0  = (unsigned long long*)ws;
  unsigned long long* h1x    = (unsigned long long*)(ws + 12582912);
  int* claim = (int*)(ws + 12584960);
  unsigned long long* l0fast = (unsigned long long*)(ws + 12584992);
  unsigned long long* h1fast = (unsigned long long*)(ws + 12587040);

  gather_emb<<<2048, 256, 0, stream>>>(tokens, (const float4*)emb, (float4*)X);

  // Layer 0 input projections (K=512); b-direction reads X time-reversed.
  gemm_proj<<<dim3(16, 64, 2), 256, 0, stream>>>(
      X, X, 1, fWih0, bWih0, fbih0, fbhh0, bbih0, bbhh0, P0f, P0b, 512);

  // Reset exchange buffers (tag 0 = "not ready" / "h[-1]=0") + claim table.
  hipMemsetAsync(ring0, 0, (size_t)2 * T_SEQ * 256 * sizeof(unsigned long long), stream);
  hipMemsetAsync(h1x, 0, 1024 * sizeof(unsigned long long), stream);
  hipMemsetAsync(claim, 0, 32 * sizeof(int), stream);
  hipMemsetAsync(l0fast, 0, 2048 * sizeof(unsigned long long), stream);

  // Fused recurrence: 768 candidate WGs; each reads its XCD id and the claim
  // table assigns forward->first XCD, backward->second XCD, 12 roles each.
  // All other WGs exit immediately.
  lstm_fused<<<dim3(768), 512, 0, stream>>>(
      P0f, P0b, fWhh0, bWhh0,
      fWih1, fWhh1, fbih1, fbhh1,
      bWih1, bWhh1, bbih1, bbhh1,
      out, ring0, h1x, l0fast, h1fast, claim);
}

// Round 6
// 7064.448 us; speedup vs baseline: 1.1434x; 1.1434x over previous
//
#include <hip/hip_runtime.h>
#include <math.h>

#define T_SEQ 4096

__device__ __forceinline__ float sigmoidf_(float x) {
  return 1.0f / (1.0f + expf(-x));
}

__device__ __forceinline__ unsigned long long pack_h(int tag, float h) {
  return ((unsigned long long)(unsigned)tag << 32) |
         (unsigned long long)__float_as_uint(h);
}

// System-scope load: bypasses L1+L2, served at the MALL — device truth.
// R0-R5 lesson: there is NO workable "fast" cached probe for this exchange;
// sc0 probes are guaranteed L2 misses costing a full memory RTT each (48 GB
// FETCH_SIZE for a 50 MB working set), so every non-truth probe is pure waste.
// Cadence-1 truth polling detects within ~1 RTT of arrival.
__device__ __forceinline__ unsigned long long ld_mall(const unsigned long long* p) {
  unsigned long long v;
  asm volatile("global_load_dwordx2 %0, %1, off sc0 sc1\n\ts_waitcnt vmcnt(0)"
               : "=v"(v) : "v"(p) : "memory");
  return v;
}
// Publish: single system-scope store to the MALL. Fire-and-forget (publishers
// never drain vmcnt afterwards; barriers are lgkmcnt-only).
__device__ __forceinline__ void st_mall(unsigned long long* p, unsigned long long v) {
  asm volatile("global_store_dwordx2 %0, %1, off sc0 sc1"
               :: "v"(p), "v"(v) : "memory");
}
__device__ __forceinline__ float poll_mall(const unsigned long long* p, unsigned want) {
  for (;;) {
    unsigned long long v = ld_mall(p);
    if ((unsigned)(v >> 32) == want) return __uint_as_float((unsigned)v);
  }
}

// Raw workgroup barrier: drains LDS (lgkmcnt) only — publishes/prefetches
// stay in flight across barriers.
__device__ __forceinline__ void bar() {
  asm volatile("s_waitcnt lgkmcnt(0)" ::: "memory");
  __builtin_amdgcn_s_barrier();
  asm volatile("" ::: "memory");
}

// ---- named-register weight fragments + anti-rematerialization pin ----------
#define DECL_W8(p) float4 p##0, p##1, p##2, p##3, p##4, p##5, p##6, p##7
#define LOAD_W8(p, src) do { const float4* _s = (const float4*)(src); \
  p##0=_s[0]; p##1=_s[1]; p##2=_s[2]; p##3=_s[3]; \
  p##4=_s[4]; p##5=_s[5]; p##6=_s[6]; p##7=_s[7]; } while (0)
#define PIN4(v4) asm volatile("" : "+v"((v4).x), "+v"((v4).y), \
                                   "+v"((v4).z), "+v"((v4).w))
#define PIN_W8(p) do { PIN4(p##0); PIN4(p##1); PIN4(p##2); PIN4(p##3); \
  PIN4(p##4); PIN4(p##5); PIN4(p##6); PIN4(p##7); } while (0)
#define FMA4(acc, W_, H_) do { acc = fmaf((W_).x, (H_).x, acc); \
  acc = fmaf((W_).y, (H_).y, acc); acc = fmaf((W_).z, (H_).z, acc); \
  acc = fmaf((W_).w, (H_).w, acc); } while (0)

// X[t][k] = emb[tokens[t]][k], as float4
__global__ void gather_emb(const int* __restrict__ tokens,
                           const float4* __restrict__ emb4,
                           float4* __restrict__ X4) {
  int i = blockIdx.x * 256 + threadIdx.x;   // i < 4096*128
  int t = i >> 7;
  int q = i & 127;
  X4[i] = emb4[(long)tokens[t] * 128 + q];
}

// P[t][j] = bias_ih[j] + bias_hh[j] + sum_k X[src(t)][k] * W[j][k]
__global__ __launch_bounds__(256) void gemm_proj(
    const float* __restrict__ Xf, const float* __restrict__ Xb, int revb,
    const float* __restrict__ Wf, const float* __restrict__ Wb,
    const float* __restrict__ bihf, const float* __restrict__ bhhf,
    const float* __restrict__ bihb, const float* __restrict__ bhhb,
    float* __restrict__ Pf, float* __restrict__ Pb, int K)
{
  const int dirb = blockIdx.z;
  const float* X  = dirb ? Xb : Xf;
  const float* W  = dirb ? Wb : Wf;
  const float* bih = dirb ? bihb : bihf;
  const float* bhh = dirb ? bhhb : bhhf;
  float* Pp = dirb ? Pb : Pf;
  const int rev = dirb ? revb : 0;

  const int bn = blockIdx.x;   // N tile (16)
  const int bm = blockIdx.y;   // M tile (64)
  const int tid = threadIdx.x;
  const int tx = tid & 15, ty = tid >> 4;

  __shared__ float Xs[16][68];
  __shared__ float Ws[16][68];

  float acc[4][4] = {{0.f}};

  const int lrow = tid >> 2;
  const int lk4  = (tid & 3) * 4;
  const int xrow = bm * 64 + lrow;
  const int xsrc = rev ? (4095 - xrow) : xrow;
  const float* xptr = X + (long)xsrc * K + lk4;
  const float* wptr = W + (long)(bn * 64 + lrow) * K + lk4;

  for (int k0 = 0; k0 < K; k0 += 16) {
    float4 xv = *(const float4*)(xptr + k0);
    float4 wv = *(const float4*)(wptr + k0);
    __syncthreads();
    Xs[lk4 + 0][lrow] = xv.x; Xs[lk4 + 1][lrow] = xv.y;
    Xs[lk4 + 2][lrow] = xv.z; Xs[lk4 + 3][lrow] = xv.w;
    Ws[lk4 + 0][lrow] = wv.x; Ws[lk4 + 1][lrow] = wv.y;
    Ws[lk4 + 2][lrow] = wv.z; Ws[lk4 + 3][lrow] = wv.w;
    __syncthreads();
    #pragma unroll
    for (int kk = 0; kk < 16; ++kk) {
      float4 a = *(const float4*)(&Xs[kk][ty * 4]);
      float4 b = *(const float4*)(&Ws[kk][tx * 4]);
      acc[0][0] = fmaf(a.x, b.x, acc[0][0]); acc[0][1] = fmaf(a.x, b.y, acc[0][1]);
      acc[0][2] = fmaf(a.x, b.z, acc[0][2]); acc[0][3] = fmaf(a.x, b.w, acc[0][3]);
      acc[1][0] = fmaf(a.y, b.x, acc[1][0]); acc[1][1] = fmaf(a.y, b.y, acc[1][1]);
      acc[1][2] = fmaf(a.y, b.z, acc[1][2]); acc[1][3] = fmaf(a.y, b.w, acc[1][3]);
      acc[2][0] = fmaf(a.z, b.x, acc[2][0]); acc[2][1] = fmaf(a.z, b.y, acc[2][1]);
      acc[2][2] = fmaf(a.z, b.z, acc[2][2]); acc[2][3] = fmaf(a.z, b.w, acc[2][3]);
      acc[3][0] = fmaf(a.w, b.x, acc[3][0]); acc[3][1] = fmaf(a.w, b.y, acc[3][1]);
      acc[3][2] = fmaf(a.w, b.z, acc[3][2]); acc[3][3] = fmaf(a.w, b.w, acc[3][3]);
    }
  }

  const int c0 = bn * 64 + tx * 4;
  #pragma unroll
  for (int i = 0; i < 4; ++i) {
    const int r = bm * 64 + ty * 4 + i;
    float4 o4;
    o4.x = acc[i][0] + bih[c0 + 0] + bhh[c0 + 0];
    o4.y = acc[i][1] + bih[c0 + 1] + bhh[c0 + 1];
    o4.z = acc[i][2] + bih[c0 + 2] + bhh[c0 + 2];
    o4.w = acc[i][3] + bih[c0 + 3] + bhh[c0 + 3];
    *(float4*)(&Pp[(long)r * 1024 + c0]) = o4;
  }
}

// Fused 2-layer bidirectional LSTM recurrence. 24 plain WGs (12/dir); all
// h-exchange is via system-scope (MALL) stores and cadence-1 system-scope
// polls — placement-independent, no cached fast path (R0-R5: any cached
// probe is a guaranteed L2 miss costing a full memory RTT; truth probes
// detect within ~1 RTT of arrival).
//
// Roles per direction (12): r 0-3 = L0 (64 cells each), r 4-11 = L1 (32 cells
// each, K=512). Row mapping m = cell*4 + gate; i/f/g/o combine is 3 in-wave
// shuffles. 2 raw barriers per step (lgkmcnt-only).
__global__ __launch_bounds__(512, 1) void lstm_fused(
    const float* __restrict__ P0f, const float* __restrict__ P0b,
    const float* __restrict__ Whh0f, const float* __restrict__ Whh0b,
    const float* __restrict__ Wih1f, const float* __restrict__ Whh1f,
    const float* __restrict__ bih1f, const float* __restrict__ bhh1f,
    const float* __restrict__ Wih1b, const float* __restrict__ Whh1b,
    const float* __restrict__ bih1b, const float* __restrict__ bhh1b,
    float* __restrict__ out,
    unsigned long long* __restrict__ ring0,   // [2 dirs][4096][256]
    unsigned long long* __restrict__ h1x)     // [2 dirs][2 par][256]
{
  const int bx = blockIdx.x;
  const int t  = threadIdx.x;
  const int d   = bx & 1;    // 0 = forward, 1 = backward
  const int sub = bx >> 1;   // role within direction, 0..11

  __shared__ float hx[512];        // L0: h[256]; L1: h0[s] ++ h1[s-1]
  __shared__ float part[8 * 264];  // [k-slice][row m=cell*4+gate], padded

  unsigned long long* ring = ring0 + (long)d * T_SEQ * 256;

  if (sub < 4) {
    // ======================= Layer 0 (4 WGs/dir, 64 cells) ==================
    const int w = sub;
    const int wbase = w * 64;
    const float* __restrict__ P = d ? P0b : P0f;
    const float* __restrict__ W = d ? Whh0b : Whh0f;

    const int kb = t >> 6;   // k-slice 0..7 (32 k each)
    const int jg = t & 63;   // cell served by this B-thread

    // Weight rows for (cell=jg, gate=0..3), k-slice kb, pinned in registers.
    DECL_W8(wa); DECL_W8(wb); DECL_W8(wc); DECL_W8(wd);
    LOAD_W8(wa, W + (long)(0 * 256 + wbase + jg) * 256 + kb * 32);
    LOAD_W8(wb, W + (long)(1 * 256 + wbase + jg) * 256 + kb * 32);
    LOAD_W8(wc, W + (long)(2 * 256 + wbase + jg) * 256 + kb * 32);
    LOAD_W8(wd, W + (long)(3 * 256 + wbase + jg) * 256 + kb * 32);
    PIN_W8(wa); PIN_W8(wb); PIN_W8(wc); PIN_W8(wd);

    // C-thread t<256 handles row m=t: cell=t>>2, gate=t&3.
    const long pj = (long)((t & 3) * 256 + wbase + (t >> 2));

    float pv_cur = 0.0f, c_prev = 0.0f;
    if (t < 256) { pv_cur = P[pj]; hx[t] = 0.0f; }

    for (int s = 0; s < T_SEQ; ++s) {
      // -------- A: dedicated pollers fetch sibling h(s-1) ------------------
      if (s > 0 && t >= 256 && t < 448) {
        const int q = t - 256;
        const int pcell = (q < wbase) ? q : q + 64;
        hx[pcell] = poll_mall(ring + (long)(s - 1) * 256 + pcell, (unsigned)s);
      }
      float pv_next = 0.0f;
      if (t < 256 && s + 1 < T_SEQ) pv_next = P[(long)(s + 1) * 1024 + pj];
      bar();   // Y: hx(s-1) complete (pollers + prev combine's own-cell write)

      // -------- B: matvec from pinned-register weights ---------------------
      float a0 = 0.f, a1 = 0.f, a2 = 0.f, a3 = 0.f;
      const float4* h4 = (const float4*)&hx[kb * 32];
      #define L0STEP(q) do { float4 hv = h4[q]; FMA4(a0, wa##q, hv); \
        FMA4(a1, wb##q, hv); FMA4(a2, wc##q, hv); FMA4(a3, wd##q, hv); } while (0)
      L0STEP(0); L0STEP(1); L0STEP(2); L0STEP(3);
      L0STEP(4); L0STEP(5); L0STEP(6); L0STEP(7);
      #undef L0STEP
      float4 av; av.x = a0; av.y = a1; av.z = a2; av.w = a3;
      *(float4*)(&part[kb * 264 + jg * 4]) = av;   // rows m=jg*4+gate
      bar();   // 2: part[] complete

      // -------- C: activation + in-wave quad combine + publish -------------
      if (t < 256) {
        float g = pv_cur;
        #pragma unroll
        for (int q = 0; q < 8; ++q) g += part[q * 264 + t];
        float act = ((t & 3) == 2) ? tanhf(g) : sigmoidf_(g);
        float y  = __shfl_xor(act, 1);
        float zx = __shfl_xor(act, 2);
        float zy = __shfl_xor(y, 2);
        const bool l1b = (t & 1), h1b = (t & 2);
        float i_ = h1b ? (l1b ? zy : zx) : (l1b ? y : act);
        float f_ = h1b ? (l1b ? zx : zy) : (l1b ? act : y);
        float g_ = h1b ? (l1b ? y : act) : (l1b ? zy : zx);
        float o_ = h1b ? (l1b ? act : y) : (l1b ? zx : zy);
        float c = f_ * c_prev + i_ * g_;
        c_prev = c;
        float h = o_ * tanhf(c);
        pv_cur = pv_next;
        if ((t & 3) == 0) {
          const int gc = wbase + (t >> 2);
          hx[gc] = h;                                   // own-cell LDS bypass
          st_mall(ring + (long)s * 256 + gc, pack_h(s + 1, h));
          if (s == T_SEQ - 1) {
            out[d * 256 + gc] = c;            // cell_memories layer 0
            out[1024 + d * 256 + gc] = h;     // hidden_states layer 0
          }
        }
      }
      // no barrier here: next iteration's barY orders C writes vs B reads.
    }
  } else {
    // ======================= Layer 1 (8 WGs/dir, 32 cells) ==================
    const int w1 = sub - 4;   // 0..7
    const int wbase1 = w1 * 32;
    const float* __restrict__ Wih = d ? Wih1b : Wih1f;
    const float* __restrict__ Whh = d ? Whh1b : Whh1f;
    const float* __restrict__ bih = d ? bih1b : bih1f;
    const float* __restrict__ bhh = d ? bhh1b : bhh1f;
    unsigned long long* slot = h1x + d * 512;            // [parity][256]
    float* hout = d ? (out + 2048 + (long)4095 * 512 + 256) : (out + 2048);
    const long hstr = d ? -512 : 512;

    const int kb = t >> 6;   // k-slice 0..7 (64 k each of combined K=512)
    const int jg = t & 63;   // -> 2 rows m = jg*2, jg*2+1 (m in [0,128))

    const int m0 = jg * 2, m1 = m0 + 1;
    const int j0 = (m0 & 3) * 256 + wbase1 + (m0 >> 2);
    const int j1 = (m1 & 3) * 256 + wbase1 + (m1 >> 2);
    const float* s0 = (kb < 4) ? (Wih + (long)j0 * 256 + kb * 64)
                               : (Whh + (long)j0 * 256 + (kb - 4) * 64);
    const float* s1 = (kb < 4) ? (Wih + (long)j1 * 256 + kb * 64)
                               : (Whh + (long)j1 * 256 + (kb - 4) * 64);
    DECL_W8(ua); DECL_W8(ub); DECL_W8(uc); DECL_W8(ud);
    LOAD_W8(ua, s0); LOAD_W8(ub, s0 + 32);
    LOAD_W8(uc, s1); LOAD_W8(ud, s1 + 32);
    PIN_W8(ua); PIN_W8(ub); PIN_W8(uc); PIN_W8(ud);

    float bsum = 0.0f, c_prev = 0.0f;
    if (t < 128) {   // C-thread t handles row m=t: cell=t>>2, gate=t&3
      const int j = (t & 3) * 256 + wbase1 + (t >> 2);
      bsum = bih[j] + bhh[j];
      if ((t & 3) == 0) hx[256 + wbase1 + (t >> 2)] = 0.0f;  // own h1(-1)=0
    }

    for (int s = 0; s < T_SEQ; ++s) {
      // -------- A: poll h0(s) (256) + sibling h1(s-1) (224) ----------------
      if (t >= 128 && t < 384) {
        const int c0_ = t - 128;
        hx[c0_] = poll_mall(ring + (long)s * 256 + c0_, (unsigned)(s + 1));
      } else {
        int q1 = -1;
        if (t < 128) { if ((t & 3) != 0) q1 = (t >> 2) * 3 + (t & 3) - 1; }
        else q1 = 96 + (t - 384);
        if (q1 >= 0) {
          const int pc1 = (q1 < wbase1) ? q1 : q1 + 32;
          hx[256 + pc1] = poll_mall(slot + ((s + 1) & 1) * 256 + pc1,
                                    (unsigned)s);
        }
      }
      bar();   // Y

      // -------- B: matvec over K=512 ---------------------------------------
      float a0 = 0.f, a1 = 0.f;
      const float4* h4 = (const float4*)&hx[kb * 64];
      #define L1STEPA(q) do { float4 hv = h4[q];     FMA4(a0, ua##q, hv); \
        FMA4(a1, uc##q, hv); } while (0)
      #define L1STEPB(q) do { float4 hv = h4[8 + q]; FMA4(a0, ub##q, hv); \
        FMA4(a1, ud##q, hv); } while (0)
      L1STEPA(0); L1STEPA(1); L1STEPA(2); L1STEPA(3);
      L1STEPA(4); L1STEPA(5); L1STEPA(6); L1STEPA(7);
      L1STEPB(0); L1STEPB(1); L1STEPB(2); L1STEPB(3);
      L1STEPB(4); L1STEPB(5); L1STEPB(6); L1STEPB(7);
      #undef L1STEPA
      #undef L1STEPB
      float2 av2; av2.x = a0; av2.y = a1;
      *(float2*)(&part[kb * 264 + jg * 2]) = av2;
      bar();   // 2

      // -------- C: activation + quad combine + publish ---------------------
      if (t < 128) {
        float g = bsum;
        #pragma unroll
        for (int q = 0; q < 8; ++q) g += part[q * 264 + t];
        float act = ((t & 3) == 2) ? tanhf(g) : sigmoidf_(g);
        float y  = __shfl_xor(act, 1);
        float zx = __shfl_xor(act, 2);
        float zy = __shfl_xor(y, 2);
        const bool l1b = (t & 1), h1b = (t & 2);
        float i_ = h1b ? (l1b ? zy : zx) : (l1b ? y : act);
        float f_ = h1b ? (l1b ? zx : zy) : (l1b ? act : y);
        float g_ = h1b ? (l1b ? y : act) : (l1b ? zy : zx);
        float o_ = h1b ? (l1b ? act : y) : (l1b ? zx : zy);
        float c = f_ * c_prev + i_ * g_;
        c_prev = c;
        float h = o_ * tanhf(c);
        if ((t & 3) == 0) {
          const int gc = wbase1 + (t >> 2);
          hx[256 + gc] = h;                            // own-cell LDS bypass
          st_mall(&slot[(s & 1) * 256 + gc], pack_h(s + 1, h));
          hout[(long)s * hstr + gc] = h;
          if (s == T_SEQ - 1) {
            out[512 + d * 256 + gc] = c;          // cell_memories layer 1
            out[1024 + 512 + d * 256 + gc] = h;   // hidden_states layer 1
          }
        }
      }
    }
  }
}

extern "C" void kernel_launch(void* const* d_in, const int* in_sizes, int n_in,
                              void* d_out, int out_size, void* d_ws, size_t ws_size,
                              hipStream_t stream) {
  const int*   tokens = (const int*)d_in[0];
  const float* emb    = (const float*)d_in[1];
  const float* fWih0 = (const float*)d_in[2];
  const float* fWhh0 = (const float*)d_in[3];
  const float* fbih0 = (const float*)d_in[4];
  const float* fbhh0 = (const float*)d_in[5];
  const float* fWih1 = (const float*)d_in[6];
  const float* fWhh1 = (const float*)d_in[7];
  const float* fbih1 = (const float*)d_in[8];
  const float* fbhh1 = (const float*)d_in[9];
  const float* bWih0 = (const float*)d_in[10];
  const float* bWhh0 = (const float*)d_in[11];
  const float* bbih0 = (const float*)d_in[12];
  const float* bbhh0 = (const float*)d_in[13];
  const float* bWih1 = (const float*)d_in[14];
  const float* bWhh1 = (const float*)d_in[15];
  const float* bbih1 = (const float*)d_in[16];
  const float* bbhh1 = (const float*)d_in[17];

  float* out = (float*)d_out;
  float* ws  = (float*)d_ws;

  // Workspace layout (float offsets):
  //   [0, 4194304)          h0 rings: [2 dirs][4096][256] u64 (16 MB).
  //                         X (4096x512, 8 MB) overlaps [0, 2097152) — dead
  //                         after gemm_proj; rings memset afterwards.
  //   [4194304,  8388608)   P0f (4096x1024)
  //   [8388608, 12582912)   P0b (4096x1024)
  //   [12582912, 12584960)  h1x: [2 dirs][2 par][256] u64 (8 KB)
  float* X   = ws;
  float* P0f = ws + 4194304;
  float* P0b = ws + 8388608;
  unsigned long long* ring0 = (unsigned long long*)ws;
  unsigned long long* h1x   = (unsigned long long*)(ws + 12582912);

  gather_emb<<<2048, 256, 0, stream>>>(tokens, (const float4*)emb, (float4*)X);

  // Layer 0 input projections (K=512); b-direction reads X time-reversed.
  gemm_proj<<<dim3(16, 64, 2), 256, 0, stream>>>(
      X, X, 1, fWih0, bWih0, fbih0, fbhh0, bbih0, bbhh0, P0f, P0b, 512);

  // Reset exchange buffers (tag 0 = "not ready" / "h[-1]=0").
  hipMemsetAsync(ring0, 0, (size_t)2 * T_SEQ * 256 * sizeof(unsigned long long), stream);
  hipMemsetAsync(h1x, 0, 1024 * sizeof(unsigned long long), stream);

  // Fused recurrence: 24 WGs (12 per direction), placement-independent.
  lstm_fused<<<dim3(24), 512, 0, stream>>>(
      P0f, P0b, fWhh0, bWhh0,
      fWih1, fWhh1, fbih1, fbhh1,
      bWih1, bWhh1, bbih1, bbhh1,
      out, ring0, h1x);
}